// Round 3
// baseline (366.051 us; speedup 1.0000x reference)
//
#include <hip/hip_runtime.h>
#include <hip/hip_bf16.h>
#include <cstdint>
#include <cstddef>

// Problem constants: M=2048, D=1024, I=2048, E=8, TOPK=2
#define DDIM  1024
#define IDIM  2048
#define NEXP  8
#define NPAIR 4096
#define MAXT1 24     // gemm1 m-tiles (stride 256): worst case 16 + padding
#define MAXT2 40     // gemm2 m-tiles (stride 128): 32 + 8 rounding

typedef __attribute__((ext_vector_type(8))) short short8;
typedef __attribute__((ext_vector_type(4))) float floatx4;
typedef __attribute__((ext_vector_type(4))) float fvec4;

__device__ inline short8 pack8v(fvec4 a, fvec4 b) {
    union { short8 s8; __hip_bfloat162 h[4]; } u;
    u.h[0] = __float22bfloat162_rn(float2{a.x, a.y});
    u.h[1] = __float22bfloat162_rn(float2{a.z, a.w});
    u.h[2] = __float22bfloat162_rn(float2{b.x, b.y});
    u.h[3] = __float22bfloat162_rn(float2{b.z, b.w});
    return u.s8;
}

__device__ inline void gload_lds16(const unsigned short* g, unsigned short* l) {
    __builtin_amdgcn_global_load_lds((const __attribute__((address_space(1))) void*)g,
                                     (__attribute__((address_space(3))) void*)l, 16, 0, 0);
}

// XCD-aware bijective block swizzle (nwg % 8 == 0 in all our grids).
__device__ inline void xcd_swz(int gridX, int nwg, int& bx, int& by) {
    const int lin = by * gridX + bx;           // hw dispatch order (x fastest)
    const int q = nwg >> 3;
    const int swz = (lin & 7) * q + (lin >> 3);
    bx = swz % gridX; by = swz / gridX;
}

// ============================================================================
// fp32 -> bf16 convert of x,w13,w2. Job = 1024 chunks; 8 independent 16B nt
// loads in flight per thread (sched_barrier pinned). Unchanged from R1.
// jobs: w13 [0,4096), w2 [4096,6144), x [6144,6400)
// ============================================================================
__launch_bounds__(256)
__global__ void cvt_all(const fvec4* __restrict__ x, const fvec4* __restrict__ w13,
                        const fvec4* __restrict__ w2,
                        uint4* __restrict__ xb, uint4* __restrict__ w13b,
                        uint4* __restrict__ w2b) {
    const int t = threadIdx.x;
    for (int job = blockIdx.x; job < 6400; job += gridDim.x) {
        const fvec4* src; uint4* dst; int cbase;
        if (job < 4096)      { src = w13; dst = w13b; cbase = job << 10; }
        else if (job < 6144) { src = w2;  dst = w2b;  cbase = (job - 4096) << 10; }
        else                 { src = x;   dst = xb;   cbase = (job - 6144) << 10; }
        const int c0 = cbase + t;
        fvec4 a0 = __builtin_nontemporal_load(src + 2 * (c0 + 0));
        fvec4 b0 = __builtin_nontemporal_load(src + 2 * (c0 + 0) + 1);
        fvec4 a1 = __builtin_nontemporal_load(src + 2 * (c0 + 256));
        fvec4 b1 = __builtin_nontemporal_load(src + 2 * (c0 + 256) + 1);
        fvec4 a2 = __builtin_nontemporal_load(src + 2 * (c0 + 512));
        fvec4 b2 = __builtin_nontemporal_load(src + 2 * (c0 + 512) + 1);
        fvec4 a3 = __builtin_nontemporal_load(src + 2 * (c0 + 768));
        fvec4 b3 = __builtin_nontemporal_load(src + 2 * (c0 + 768) + 1);
        __builtin_amdgcn_sched_barrier(0);
        short8 p0 = pack8v(a0, b0);
        short8 p1 = pack8v(a1, b1);
        short8 p2 = pack8v(a2, b2);
        short8 p3 = pack8v(a3, b3);
        dst[c0 + 0]   = *(uint4*)&p0;
        dst[c0 + 256] = *(uint4*)&p1;
        dst[c0 + 512] = *(uint4*)&p2;
        dst[c0 + 768] = *(uint4*)&p3;
    }
}

// ============================================================================
// Routing + TWO dense tile tables: tbl1 stride 256 (gemm1), tbl2 stride 128
// (gemm2). tbl[i] = {e, mbase, off0, ne}; padded with zeros.
// ============================================================================
__global__ void route_kernel(const int* __restrict__ eidx,
                             int4* __restrict__ tbl1,
                             int4* __restrict__ tbl2,
                             int* __restrict__ slot_q) {
    __shared__ int cnt[NEXP];
    __shared__ int cur[NEXP];
    const int t = threadIdx.x;
    if (t < NEXP) cnt[t] = 0;
    __syncthreads();
    for (int q = t; q < NPAIR; q += 1024) atomicAdd(&cnt[eidx[q]], 1);
    __syncthreads();
    if (t == 0) {
        int s = 0, n1 = 0, n2 = 0;
        for (int e = 0; e < NEXP; e++) {
            cur[e] = s;
            for (int mb = 0; mb < cnt[e]; mb += 256)
                tbl1[n1++] = int4{e, mb, s, cnt[e]};
            for (int mb = 0; mb < cnt[e]; mb += 128)
                tbl2[n2++] = int4{e, mb, s, cnt[e]};
            s += cnt[e];
        }
        for (; n1 < MAXT1; n1++) tbl1[n1] = int4{0, 0, 0, 0};
        for (; n2 < MAXT2; n2++) tbl2[n2] = int4{0, 0, 0, 0};
    }
    __syncthreads();
    for (int q = t; q < NPAIR; q += 1024) {
        int e = eidx[q];
        int pos = atomicAdd(&cur[e], 1);
        slot_q[pos] = q;
    }
}

// ============================================================================
// GEMM1 + SwiGLU v2: BM=256, BN_out=128 (256 B-rows: 128 w1 + 128 w3), BK=64.
// 512 threads = 8 waves (2M x 4N); per-wave 128M x 32 out-cols.
// LDS 64KB: As 256x64, Bs 256x64, XOR-8 swizzle, global_load_lds staging.
// grid: (IDIM/128=16, MAXT1) + XCD swizzle. Traffic ~330MB (was ~590MB).
// ============================================================================
__launch_bounds__(512)
__global__ void gemm1_swiglu(const unsigned short* __restrict__ xb,
                             const unsigned short* __restrict__ w13b,
                             const int4* __restrict__ tbl,
                             const int* __restrict__ slot_q,
                             unsigned short* __restrict__ pbuf) {
    int bx = blockIdx.x, by = blockIdx.y;
    xcd_swz(16, 16 * MAXT1, bx, by);
    const int4 tt = tbl[by];
    const int e = tt.x, mbase = tt.y, off0 = tt.z, ne = tt.w;
    if (mbase >= ne) return;
    const int n0 = bx * 128;

    __shared__ __align__(16) unsigned short As[256 * 64];
    __shared__ __align__(16) unsigned short Bs[256 * 64];

    const int t    = threadIdx.x;
    const int lane = t & 63;
    const int wid  = t >> 6;

    // staging: 512 thr, 8 chunks/row -> 64 rows per issue; 4 issues each op.
    const int rr = t >> 3;                      // 0..63
    const int g  = (t & 7) ^ (rr & 7);
    const unsigned short* pA[4];
    const unsigned short* pB[4];
    const unsigned short* wb1 = w13b + (size_t)e * (2 * IDIM) * DDIM;
    #pragma unroll
    for (int c = 0; c < 4; c++) {
        int row = c * 64 + rr;                  // 0..255
        int sl = mbase + row; if (sl > ne - 1) sl = ne - 1;
        pA[c] = xb + (size_t)(slot_q[off0 + sl] >> 1) * DDIM + g * 8;
        int wrow = (row < 128) ? (n0 + row) : (IDIM + n0 + (row - 128)); // w1|w3
        pB[c] = wb1 + (size_t)wrow * DDIM + g * 8;
    }
    unsigned short* lA = As + wid * 512;        // + c*4096
    unsigned short* lB = Bs + wid * 512;

    const int wm = wid >> 2, wn = wid & 3;      // 2M x 4N
    const int quad = lane >> 4, l16 = lane & 15;
    const int rsw = l16 & 7;
    const int co0 = (quad ^ rsw) * 8;
    const int co1 = ((quad + 4) ^ rsw) * 8;

    floatx4 acc1[8][2], acc3[8][2];
    #pragma unroll
    for (int i = 0; i < 8; i++)
        #pragma unroll
        for (int j = 0; j < 2; j++) {
            acc1[i][j] = floatx4{0.f, 0.f, 0.f, 0.f};
            acc3[i][j] = floatx4{0.f, 0.f, 0.f, 0.f};
        }

    for (int it = 0; it < DDIM / 64; ++it) {    // 16 K-steps
        const int ko = it * 64;
        __syncthreads();
        #pragma unroll
        for (int c = 0; c < 4; c++) {
            gload_lds16(pA[c] + ko, lA + c * 4096);
            gload_lds16(pB[c] + ko, lB + c * 4096);
        }
        __syncthreads();

        #pragma unroll
        for (int h = 0; h < 2; ++h) {
            const int co = h ? co1 : co0;
            short8 af[8], b1f[2], b3f[2];
            #pragma unroll
            for (int mi = 0; mi < 8; mi++)
                af[mi] = *(short8*)&As[(wm * 128 + mi * 16 + l16) * 64 + co];
            #pragma unroll
            for (int ni = 0; ni < 2; ni++) {
                b1f[ni] = *(short8*)&Bs[(wn * 32 + ni * 16 + l16) * 64 + co];
                b3f[ni] = *(short8*)&Bs[(128 + wn * 32 + ni * 16 + l16) * 64 + co];
            }
            #pragma unroll
            for (int mi = 0; mi < 8; mi++)
                #pragma unroll
                for (int ni = 0; ni < 2; ni++) {
                    acc1[mi][ni] = __builtin_amdgcn_mfma_f32_16x16x32_bf16(af[mi], b1f[ni], acc1[mi][ni], 0, 0, 0);
                    acc3[mi][ni] = __builtin_amdgcn_mfma_f32_16x16x32_bf16(af[mi], b3f[ni], acc3[mi][ni], 0, 0, 0);
                }
        }
    }

    #pragma unroll
    for (int mi = 0; mi < 8; mi++) {
        #pragma unroll
        for (int ni = 0; ni < 2; ni++) {
            const int col = n0 + wn * 32 + ni * 16 + l16;
            #pragma unroll
            for (int rw = 0; rw < 4; rw++) {
                const int s2 = mbase + wm * 128 + mi * 16 + quad * 4 + rw;
                if (s2 < ne) {
                    float v1 = acc1[mi][ni][rw];
                    float v3 = acc3[mi][ni][rw];
                    float pv = v1 / (1.f + __expf(-v1)) * v3;
                    __hip_bfloat16 pb = __float2bfloat16(pv);
                    pbuf[(size_t)(off0 + s2) * IDIM + col] = *(unsigned short*)&pb;
                }
            }
        }
    }
}

// ============================================================================
// GEMM2 v2: BM=128, BN=128, full K=2048, direct fp32 store to out.
// 256 threads, 32KB LDS. grid: (DDIM/128=8, MAXT2) + XCD swizzle.
// Traffic ~265MB (was ~390MB).
// ============================================================================
__launch_bounds__(256)
__global__ void gemm2_out(const unsigned short* __restrict__ pbuf,
                          const unsigned short* __restrict__ w2b,
                          const int4* __restrict__ tbl,
                          const int* __restrict__ slot_q,
                          float* __restrict__ out) {
    int bx = blockIdx.x, by = blockIdx.y;
    xcd_swz(8, 8 * MAXT2, bx, by);
    const int4 tt = tbl[by];
    const int e = tt.x, mbase = tt.y, off0 = tt.z, ne = tt.w;
    if (mbase >= ne) return;
    const int n0 = bx * 128;

    __shared__ __align__(16) unsigned short As[128 * 64];
    __shared__ __align__(16) unsigned short Bs[128 * 64];

    const int t    = threadIdx.x;
    const int lane = t & 63;
    const int wid  = t >> 6;

    const int rr = t >> 3;                      // 0..31
    const int g  = (t & 7) ^ (rr & 7);
    const unsigned short* pA[4];
    const unsigned short* pB[4];
    const unsigned short* wb = w2b + (size_t)e * DDIM * IDIM;
    #pragma unroll
    for (int c = 0; c < 4; c++) {
        int row = c * 32 + rr;                  // 0..127
        int sl = mbase + row; if (sl > ne - 1) sl = ne - 1;
        pA[c] = pbuf + (size_t)(off0 + sl) * IDIM + g * 8;
        pB[c] = wb + (size_t)(n0 + row) * IDIM + g * 8;
    }
    unsigned short* lA = As + wid * 512;
    unsigned short* lB = Bs + wid * 512;

    const int wm = wid >> 1, wn = wid & 1;
    const int quad = lane >> 4, l16 = lane & 15;
    const int rsw = l16 & 7;
    const int co0 = (quad ^ rsw) * 8;
    const int co1 = ((quad + 4) ^ rsw) * 8;

    floatx4 acc[4][4];
    #pragma unroll
    for (int i = 0; i < 4; i++)
        #pragma unroll
        for (int j = 0; j < 4; j++) acc[i][j] = floatx4{0.f, 0.f, 0.f, 0.f};

    for (int it = 0; it < IDIM / 64; ++it) {    // 32 K-steps, full K
        const int ko = it * 64;
        __syncthreads();
        #pragma unroll
        for (int c = 0; c < 4; c++) {
            gload_lds16(pA[c] + ko, lA + c * 2048);
            gload_lds16(pB[c] + ko, lB + c * 2048);
        }
        __syncthreads();

        #pragma unroll
        for (int h = 0; h < 2; ++h) {
            const int co = h ? co1 : co0;
            short8 af[4], bf[4];
            #pragma unroll
            for (int mi = 0; mi < 4; mi++)
                af[mi] = *(short8*)&As[(wm * 64 + mi * 16 + l16) * 64 + co];
            #pragma unroll
            for (int ni = 0; ni < 4; ni++)
                bf[ni] = *(short8*)&Bs[(wn * 64 + ni * 16 + l16) * 64 + co];
            #pragma unroll
            for (int mi = 0; mi < 4; mi++)
                #pragma unroll
                for (int ni = 0; ni < 4; ni++)
                    acc[mi][ni] = __builtin_amdgcn_mfma_f32_16x16x32_bf16(af[mi], bf[ni], acc[mi][ni], 0, 0, 0);
        }
    }

    #pragma unroll
    for (int mi = 0; mi < 4; mi++) {
        #pragma unroll
        for (int rw = 0; rw < 4; rw++) {
            const int s2 = mbase + wm * 64 + mi * 16 + quad * 4 + rw;
            if (s2 < ne) {
                const int qq = slot_q[off0 + s2];
                float* orow = out + (size_t)qq * DDIM;
                #pragma unroll
                for (int ni = 0; ni < 4; ni++)
                    orow[n0 + wn * 64 + ni * 16 + l16] = acc[mi][ni][rw];
            }
        }
    }
}

// ============================================================================
extern "C" void kernel_launch(void* const* d_in, const int* in_sizes, int n_in,
                              void* d_out, int out_size, void* d_ws, size_t ws_size,
                              hipStream_t stream) {
    const float* x    = (const float*)d_in[0];
    const float* w13  = (const float*)d_in[1];
    const float* w2   = (const float*)d_in[2];
    const int*   eidx = (const int*)d_in[3];
    float* out = (float*)d_out;

    // ws layout:
    //   [128,512) tbl1; [2048,2688) tbl2; [4096,20480) slot_q;
    //   [OFF_XB,+4MB) xb; [OFF_W13B,+64MB) w13b; [OFF_W2B,+32MB) w2b;
    //   [OFF_PBUF,+16MB) pbuf   (NEED ~116MB)
    const size_t OFF_XB   = 65536;
    const size_t OFF_W13B = OFF_XB + (size_t)4 * 1024 * 1024;
    const size_t OFF_W2B  = OFF_W13B + (size_t)64 * 1024 * 1024;
    const size_t OFF_PBUF = OFF_W2B + (size_t)32 * 1024 * 1024;

    int4* tbl1  = (int4*)((char*)d_ws + 128);
    int4* tbl2  = (int4*)((char*)d_ws + 2048);
    int* slot_q = (int*)((char*)d_ws + 4096);
    unsigned short* xb   = (unsigned short*)((char*)d_ws + OFF_XB);
    unsigned short* w13b = (unsigned short*)((char*)d_ws + OFF_W13B);
    unsigned short* w2b  = (unsigned short*)((char*)d_ws + OFF_W2B);
    unsigned short* pbuf = (unsigned short*)((char*)d_ws + OFF_PBUF);

    hipLaunchKernelGGL(route_kernel, dim3(1), dim3(1024), 0, stream, eidx, tbl1, tbl2, slot_q);
    hipLaunchKernelGGL(cvt_all, dim3(6400), dim3(256), 0, stream,
                       (const fvec4*)x, (const fvec4*)w13, (const fvec4*)w2,
                       (uint4*)xb, (uint4*)w13b, (uint4*)w2b);
    hipLaunchKernelGGL(gemm1_swiglu, dim3(IDIM / 128, MAXT1), dim3(512), 0, stream,
                       xb, w13b, tbl1, slot_q, pbuf);
    hipLaunchKernelGGL(gemm2_out, dim3(DDIM / 128, MAXT2), dim3(256), 0, stream,
                       pbuf, w2b, tbl2, slot_q, out);
}

// Round 4
// 343.955 us; speedup vs baseline: 1.0642x; 1.0642x over previous
//
#include <hip/hip_runtime.h>
#include <hip/hip_bf16.h>
#include <cstdint>
#include <cstddef>

// Problem constants: M=2048, D=1024, I=2048, E=8, TOPK=2
#define DDIM  1024
#define IDIM  2048
#define NEXP  8
#define NPAIR 4096
#define MAXTILE 40   // m-tiles (stride 128): 32 + 8 rounding

typedef __attribute__((ext_vector_type(8))) short short8;
typedef __attribute__((ext_vector_type(4))) float floatx4;
typedef __attribute__((ext_vector_type(4))) float fvec4;

__device__ inline short8 pack8v(fvec4 a, fvec4 b) {
    union { short8 s8; __hip_bfloat162 h[4]; } u;
    u.h[0] = __float22bfloat162_rn(float2{a.x, a.y});
    u.h[1] = __float22bfloat162_rn(float2{a.z, a.w});
    u.h[2] = __float22bfloat162_rn(float2{b.x, b.y});
    u.h[3] = __float22bfloat162_rn(float2{b.z, b.w});
    return u.s8;
}

__device__ inline void gload_lds16(const unsigned short* g, unsigned short* l) {
    __builtin_amdgcn_global_load_lds((const __attribute__((address_space(1))) void*)g,
                                     (__attribute__((address_space(3))) void*)l, 16, 0, 0);
}

// ============================================================================
// fp32 -> bf16 convert of x,w13,w2. Job = 1024 chunks; 8 independent 16B nt
// loads in flight per thread (sched_barrier pinned). Unchanged from R1.
// jobs: w13 [0,4096), w2 [4096,6144), x [6144,6400)
// ============================================================================
__launch_bounds__(256)
__global__ void cvt_all(const fvec4* __restrict__ x, const fvec4* __restrict__ w13,
                        const fvec4* __restrict__ w2,
                        uint4* __restrict__ xb, uint4* __restrict__ w13b,
                        uint4* __restrict__ w2b) {
    const int t = threadIdx.x;
    for (int job = blockIdx.x; job < 6400; job += gridDim.x) {
        const fvec4* src; uint4* dst; int cbase;
        if (job < 4096)      { src = w13; dst = w13b; cbase = job << 10; }
        else if (job < 6144) { src = w2;  dst = w2b;  cbase = (job - 4096) << 10; }
        else                 { src = x;   dst = xb;   cbase = (job - 6144) << 10; }
        const int c0 = cbase + t;
        fvec4 a0 = __builtin_nontemporal_load(src + 2 * (c0 + 0));
        fvec4 b0 = __builtin_nontemporal_load(src + 2 * (c0 + 0) + 1);
        fvec4 a1 = __builtin_nontemporal_load(src + 2 * (c0 + 256));
        fvec4 b1 = __builtin_nontemporal_load(src + 2 * (c0 + 256) + 1);
        fvec4 a2 = __builtin_nontemporal_load(src + 2 * (c0 + 512));
        fvec4 b2 = __builtin_nontemporal_load(src + 2 * (c0 + 512) + 1);
        fvec4 a3 = __builtin_nontemporal_load(src + 2 * (c0 + 768));
        fvec4 b3 = __builtin_nontemporal_load(src + 2 * (c0 + 768) + 1);
        __builtin_amdgcn_sched_barrier(0);
        short8 p0 = pack8v(a0, b0);
        short8 p1 = pack8v(a1, b1);
        short8 p2 = pack8v(a2, b2);
        short8 p3 = pack8v(a3, b3);
        dst[c0 + 0]   = *(uint4*)&p0;
        dst[c0 + 256] = *(uint4*)&p1;
        dst[c0 + 512] = *(uint4*)&p2;
        dst[c0 + 768] = *(uint4*)&p3;
    }
}

// ============================================================================
// Routing + dense tile table (stride 128). tbl[i] = {e, mbase, off0, ne}.
// ============================================================================
__global__ void route_kernel(const int* __restrict__ eidx,
                             int4* __restrict__ tbl,
                             int* __restrict__ slot_q) {
    __shared__ int cnt[NEXP];
    __shared__ int cur[NEXP];
    const int t = threadIdx.x;
    if (t < NEXP) cnt[t] = 0;
    __syncthreads();
    for (int q = t; q < NPAIR; q += 1024) atomicAdd(&cnt[eidx[q]], 1);
    __syncthreads();
    if (t == 0) {
        int s = 0, nt = 0;
        for (int e = 0; e < NEXP; e++) {
            cur[e] = s;
            for (int mb = 0; mb < cnt[e]; mb += 128)
                tbl[nt++] = int4{e, mb, s, cnt[e]};
            s += cnt[e];
        }
        for (; nt < MAXTILE; nt++) tbl[nt] = int4{0, 0, 0, 0};
    }
    __syncthreads();
    for (int q = t; q < NPAIR; q += 1024) {
        int e = eidx[q];
        int pos = atomicAdd(&cur[e], 1);
        slot_q[pos] = q;
    }
}

// ============================================================================
// GEMM1 + SwiGLU: 128(M) x 64(N out) tile, BK=64, 2-phase double-buffered
// pipeline (T3-min): prefetch tile t+1 issued BEFORE compute of tile t;
// ONE raw s_barrier + vmcnt(0) per K-step (no compiler-forced double drain).
// LDS 64KB (2 bufs x (As 16K + Bs 16K)) -> 2 blocks/CU. grid (32, MAXTILE).
// XOR-8 swizzle staging identical to R2 (bank-conflict-free, verified 0).
// ============================================================================
__launch_bounds__(256)
__global__ void gemm1_swiglu(const unsigned short* __restrict__ xb,
                             const unsigned short* __restrict__ w13b,
                             const int4* __restrict__ tbl,
                             const int* __restrict__ slot_q,
                             unsigned short* __restrict__ pbuf) {
    const int4 tt = tbl[blockIdx.y];
    const int e = tt.x, mbase = tt.y, off0 = tt.z, ne = tt.w;
    if (mbase >= ne) return;
    const int n0 = blockIdx.x * 64;

    __shared__ __align__(16) unsigned short As[2][128 * 64];
    __shared__ __align__(16) unsigned short Bs[2][128 * 64];

    const int t    = threadIdx.x;
    const int lane = t & 63;
    const int wid  = t >> 6;

    const int rr = t >> 3;
    const int g  = (t & 7) ^ (rr & 7);
    const unsigned short* pA[4];
    const unsigned short* pB[4];
    const unsigned short* wb1 = w13b + (size_t)e * (2 * IDIM) * DDIM;
    #pragma unroll
    for (int c = 0; c < 4; c++) {
        int row = c * 32 + rr;                      // 0..127
        int sl = mbase + row; if (sl > ne - 1) sl = ne - 1;
        pA[c] = xb + (size_t)(slot_q[off0 + sl] >> 1) * DDIM + g * 8;
        int wrow = (row < 64) ? (n0 + row) : (IDIM + n0 + (row - 64));  // w1 | w3
        pB[c] = wb1 + (size_t)wrow * DDIM + g * 8;
    }
    const int lo = wid * 512;   // + c*2048 within each buffer

    const int wm = wid >> 1, wn = wid & 1;
    const int quad = lane >> 4, l16 = lane & 15;
    const int rsw = l16 & 7;
    const int co0 = (quad ^ rsw) * 8;
    const int co1 = ((quad + 4) ^ rsw) * 8;

    floatx4 acc1[4][2], acc3[4][2];
    #pragma unroll
    for (int i = 0; i < 4; i++)
        #pragma unroll
        for (int j = 0; j < 2; j++) {
            acc1[i][j] = floatx4{0.f, 0.f, 0.f, 0.f};
            acc3[i][j] = floatx4{0.f, 0.f, 0.f, 0.f};
        }

    // prologue: stage tile 0 into buf 0, drain, barrier
    #pragma unroll
    for (int c = 0; c < 4; c++) {
        gload_lds16(pA[c], &As[0][lo + c * 2048]);
        gload_lds16(pB[c], &Bs[0][lo + c * 2048]);
    }
    asm volatile("s_waitcnt vmcnt(0)" ::: "memory");
    __builtin_amdgcn_s_barrier();
    __builtin_amdgcn_sched_barrier(0);

    int cur = 0;
    for (int it = 0; it < DDIM / 64; ++it) {        // 16 K-steps
        if (it + 1 < DDIM / 64) {                   // prefetch next tile
            const int ko = (it + 1) * 64;
            #pragma unroll
            for (int c = 0; c < 4; c++) {
                gload_lds16(pA[c] + ko, &As[cur ^ 1][lo + c * 2048]);
                gload_lds16(pB[c] + ko, &Bs[cur ^ 1][lo + c * 2048]);
            }
        }
        __builtin_amdgcn_s_setprio(1);
        #pragma unroll
        for (int h = 0; h < 2; ++h) {
            const int co = h ? co1 : co0;
            short8 af[4], b1f[2], b3f[2];
            #pragma unroll
            for (int mi = 0; mi < 4; mi++)
                af[mi] = *(short8*)&As[cur][(wm * 64 + mi * 16 + l16) * 64 + co];
            #pragma unroll
            for (int ni = 0; ni < 2; ni++) {
                b1f[ni] = *(short8*)&Bs[cur][(wn * 32 + ni * 16 + l16) * 64 + co];
                b3f[ni] = *(short8*)&Bs[cur][(64 + wn * 32 + ni * 16 + l16) * 64 + co];
            }
            #pragma unroll
            for (int mi = 0; mi < 4; mi++)
                #pragma unroll
                for (int ni = 0; ni < 2; ni++) {
                    acc1[mi][ni] = __builtin_amdgcn_mfma_f32_16x16x32_bf16(af[mi], b1f[ni], acc1[mi][ni], 0, 0, 0);
                    acc3[mi][ni] = __builtin_amdgcn_mfma_f32_16x16x32_bf16(af[mi], b3f[ni], acc3[mi][ni], 0, 0, 0);
                }
        }
        __builtin_amdgcn_s_setprio(0);
        asm volatile("s_waitcnt vmcnt(0)" ::: "memory");
        __builtin_amdgcn_s_barrier();
        __builtin_amdgcn_sched_barrier(0);
        cur ^= 1;
    }

    #pragma unroll
    for (int mi = 0; mi < 4; mi++) {
        #pragma unroll
        for (int ni = 0; ni < 2; ni++) {
            const int col = n0 + wn * 32 + ni * 16 + l16;
            #pragma unroll
            for (int rw = 0; rw < 4; rw++) {
                const int s2 = mbase + wm * 64 + mi * 16 + quad * 4 + rw;
                if (s2 < ne) {
                    float v1 = acc1[mi][ni][rw];
                    float v3 = acc3[mi][ni][rw];
                    float pv = v1 / (1.f + __expf(-v1)) * v3;
                    __hip_bfloat16 pb = __float2bfloat16(pv);
                    pbuf[(size_t)(off0 + s2) * IDIM + col] = *(unsigned short*)&pb;
                }
            }
        }
    }
}

// ============================================================================
// GEMM2: 128(M) x 64(N) tile, full K=2048, direct fp32 store to out.
// Same 2-phase double-buffered pipeline. LDS 48KB (2 x (As 16K + Bs 8K))
// -> 3 blocks/CU. grid (16, MAXTILE), ~544 live blocks.
// ============================================================================
__launch_bounds__(256)
__global__ void gemm2_out(const unsigned short* __restrict__ pbuf,
                          const unsigned short* __restrict__ w2b,
                          const int4* __restrict__ tbl,
                          const int* __restrict__ slot_q,
                          float* __restrict__ out) {
    const int4 tt = tbl[blockIdx.y];
    const int e = tt.x, mbase = tt.y, off0 = tt.z, ne = tt.w;
    if (mbase >= ne) return;
    const int n0 = blockIdx.x * 64;

    __shared__ __align__(16) unsigned short As[2][128 * 64];
    __shared__ __align__(16) unsigned short Bs[2][64 * 64];

    const int t    = threadIdx.x;
    const int lane = t & 63;
    const int wid  = t >> 6;

    const int rr = t >> 3;
    const int g  = (t & 7) ^ (rr & 7);
    const unsigned short* pA[4];
    const unsigned short* pB[2];
    const unsigned short* wb = w2b + (size_t)e * DDIM * IDIM;
    #pragma unroll
    for (int c = 0; c < 4; c++) {
        int row = c * 32 + rr;                      // 0..127
        int sl = mbase + row; if (sl > ne - 1) sl = ne - 1;
        pA[c] = pbuf + (size_t)(off0 + sl) * IDIM + g * 8;
    }
    #pragma unroll
    for (int c = 0; c < 2; c++) {
        int row = c * 32 + rr;                      // 0..63
        pB[c] = wb + (size_t)(n0 + row) * IDIM + g * 8;
    }
    const int lo = wid * 512;

    const int wm = wid >> 1, wn = wid & 1;
    const int quad = lane >> 4, l16 = lane & 15;
    const int rsw = l16 & 7;
    const int co0 = (quad ^ rsw) * 8;
    const int co1 = ((quad + 4) ^ rsw) * 8;

    floatx4 acc[4][2];
    #pragma unroll
    for (int i = 0; i < 4; i++)
        #pragma unroll
        for (int j = 0; j < 2; j++) acc[i][j] = floatx4{0.f, 0.f, 0.f, 0.f};

    // prologue
    #pragma unroll
    for (int c = 0; c < 4; c++)
        gload_lds16(pA[c], &As[0][lo + c * 2048]);
    #pragma unroll
    for (int c = 0; c < 2; c++)
        gload_lds16(pB[c], &Bs[0][lo + c * 2048]);
    asm volatile("s_waitcnt vmcnt(0)" ::: "memory");
    __builtin_amdgcn_s_barrier();
    __builtin_amdgcn_sched_barrier(0);

    int cur = 0;
    for (int it = 0; it < IDIM / 64; ++it) {        // 32 K-steps
        if (it + 1 < IDIM / 64) {
            const int ko = (it + 1) * 64;
            #pragma unroll
            for (int c = 0; c < 4; c++)
                gload_lds16(pA[c] + ko, &As[cur ^ 1][lo + c * 2048]);
            #pragma unroll
            for (int c = 0; c < 2; c++)
                gload_lds16(pB[c] + ko, &Bs[cur ^ 1][lo + c * 2048]);
        }
        __builtin_amdgcn_s_setprio(1);
        #pragma unroll
        for (int h = 0; h < 2; ++h) {
            const int co = h ? co1 : co0;
            short8 af[4], bf[2];
            #pragma unroll
            for (int mi = 0; mi < 4; mi++)
                af[mi] = *(short8*)&As[cur][(wm * 64 + mi * 16 + l16) * 64 + co];
            #pragma unroll
            for (int ni = 0; ni < 2; ni++)
                bf[ni] = *(short8*)&Bs[cur][(wn * 32 + ni * 16 + l16) * 64 + co];
            #pragma unroll
            for (int mi = 0; mi < 4; mi++)
                #pragma unroll
                for (int ni = 0; ni < 2; ni++)
                    acc[mi][ni] = __builtin_amdgcn_mfma_f32_16x16x32_bf16(af[mi], bf[ni], acc[mi][ni], 0, 0, 0);
        }
        __builtin_amdgcn_s_setprio(0);
        asm volatile("s_waitcnt vmcnt(0)" ::: "memory");
        __builtin_amdgcn_s_barrier();
        __builtin_amdgcn_sched_barrier(0);
        cur ^= 1;
    }

    #pragma unroll
    for (int mi = 0; mi < 4; mi++) {
        #pragma unroll
        for (int rw = 0; rw < 4; rw++) {
            const int s2 = mbase + wm * 64 + mi * 16 + quad * 4 + rw;
            if (s2 < ne) {
                const int qq = slot_q[off0 + s2];
                float* orow = out + (size_t)qq * DDIM;
                #pragma unroll
                for (int ni = 0; ni < 2; ni++)
                    orow[n0 + wn * 32 + ni * 16 + l16] = acc[mi][ni][rw];
            }
        }
    }
}

// ============================================================================
extern "C" void kernel_launch(void* const* d_in, const int* in_sizes, int n_in,
                              void* d_out, int out_size, void* d_ws, size_t ws_size,
                              hipStream_t stream) {
    const float* x    = (const float*)d_in[0];
    const float* w13  = (const float*)d_in[1];
    const float* w2   = (const float*)d_in[2];
    const int*   eidx = (const int*)d_in[3];
    float* out = (float*)d_out;

    // ws layout:
    //   [128,768) tile tbl; [1024,17408) slot_q; [OFF_XB,+4MB) xb;
    //   [OFF_W13B,+64MB) w13b; [OFF_W2B,+32MB) w2b; [OFF_PBUF,+16MB) pbuf
    const size_t OFF_XB   = 65536;
    const size_t OFF_W13B = OFF_XB + (size_t)4 * 1024 * 1024;
    const size_t OFF_W2B  = OFF_W13B + (size_t)64 * 1024 * 1024;
    const size_t OFF_PBUF = OFF_W2B + (size_t)32 * 1024 * 1024;

    int4* tbl   = (int4*)((char*)d_ws + 128);
    int* slot_q = (int*)((char*)d_ws + 1024);
    unsigned short* xb   = (unsigned short*)((char*)d_ws + OFF_XB);
    unsigned short* w13b = (unsigned short*)((char*)d_ws + OFF_W13B);
    unsigned short* w2b  = (unsigned short*)((char*)d_ws + OFF_W2B);
    unsigned short* pbuf = (unsigned short*)((char*)d_ws + OFF_PBUF);

    hipLaunchKernelGGL(route_kernel, dim3(1), dim3(1024), 0, stream, eidx, tbl, slot_q);
    hipLaunchKernelGGL(cvt_all, dim3(6400), dim3(256), 0, stream,
                       (const fvec4*)x, (const fvec4*)w13, (const fvec4*)w2,
                       (uint4*)xb, (uint4*)w13b, (uint4*)w2b);
    hipLaunchKernelGGL(gemm1_swiglu, dim3(IDIM / 64, MAXTILE), dim3(256), 0, stream,
                       xb, w13b, tbl, slot_q, pbuf);
    hipLaunchKernelGGL(gemm2_out, dim3(DDIM / 64, MAXTILE), dim3(256), 0, stream,
                       pbuf, w2b, tbl, slot_q, out);
}

// Round 5
// 341.090 us; speedup vs baseline: 1.0732x; 1.0084x over previous
//
#include <hip/hip_runtime.h>
#include <hip/hip_bf16.h>
#include <cstdint>
#include <cstddef>

// Problem constants: M=2048, D=1024, I=2048, E=8, TOPK=2
#define DDIM  1024
#define IDIM  2048
#define NEXP  8
#define NPAIR 4096
#define MAXTILE 40   // m-tiles (stride 128): 32 + 8 rounding

typedef __attribute__((ext_vector_type(8))) short short8;
typedef __attribute__((ext_vector_type(4))) float floatx4;
typedef __attribute__((ext_vector_type(4))) float fvec4;

__device__ inline short8 pack8v(fvec4 a, fvec4 b) {
    union { short8 s8; __hip_bfloat162 h[4]; } u;
    u.h[0] = __float22bfloat162_rn(float2{a.x, a.y});
    u.h[1] = __float22bfloat162_rn(float2{a.z, a.w});
    u.h[2] = __float22bfloat162_rn(float2{b.x, b.y});
    u.h[3] = __float22bfloat162_rn(float2{b.z, b.w});
    return u.s8;
}

__device__ inline void gload_lds16(const unsigned short* g, unsigned short* l) {
    __builtin_amdgcn_global_load_lds((const __attribute__((address_space(1))) void*)g,
                                     (__attribute__((address_space(3))) void*)l, 16, 0, 0);
}

// ============================================================================
// fp32 -> bf16 convert of x,w13,w2. Job = 1024 chunks; 8 independent 16B nt
// loads in flight per thread (sched_barrier pinned). Unchanged from R1.
// jobs: w13 [0,4096), w2 [4096,6144), x [6144,6400)
// ============================================================================
__launch_bounds__(256)
__global__ void cvt_all(const fvec4* __restrict__ x, const fvec4* __restrict__ w13,
                        const fvec4* __restrict__ w2,
                        uint4* __restrict__ xb, uint4* __restrict__ w13b,
                        uint4* __restrict__ w2b) {
    const int t = threadIdx.x;
    for (int job = blockIdx.x; job < 6400; job += gridDim.x) {
        const fvec4* src; uint4* dst; int cbase;
        if (job < 4096)      { src = w13; dst = w13b; cbase = job << 10; }
        else if (job < 6144) { src = w2;  dst = w2b;  cbase = (job - 4096) << 10; }
        else                 { src = x;   dst = xb;   cbase = (job - 6144) << 10; }
        const int c0 = cbase + t;
        fvec4 a0 = __builtin_nontemporal_load(src + 2 * (c0 + 0));
        fvec4 b0 = __builtin_nontemporal_load(src + 2 * (c0 + 0) + 1);
        fvec4 a1 = __builtin_nontemporal_load(src + 2 * (c0 + 256));
        fvec4 b1 = __builtin_nontemporal_load(src + 2 * (c0 + 256) + 1);
        fvec4 a2 = __builtin_nontemporal_load(src + 2 * (c0 + 512));
        fvec4 b2 = __builtin_nontemporal_load(src + 2 * (c0 + 512) + 1);
        fvec4 a3 = __builtin_nontemporal_load(src + 2 * (c0 + 768));
        fvec4 b3 = __builtin_nontemporal_load(src + 2 * (c0 + 768) + 1);
        __builtin_amdgcn_sched_barrier(0);
        short8 p0 = pack8v(a0, b0);
        short8 p1 = pack8v(a1, b1);
        short8 p2 = pack8v(a2, b2);
        short8 p3 = pack8v(a3, b3);
        dst[c0 + 0]   = *(uint4*)&p0;
        dst[c0 + 256] = *(uint4*)&p1;
        dst[c0 + 512] = *(uint4*)&p2;
        dst[c0 + 768] = *(uint4*)&p3;
    }
}

// ============================================================================
// Routing + dense tile table (stride 128). tbl[i] = {e, mbase, off0, ne}.
// ============================================================================
__global__ void route_kernel(const int* __restrict__ eidx,
                             int4* __restrict__ tbl,
                             int* __restrict__ slot_q) {
    __shared__ int cnt[NEXP];
    __shared__ int cur[NEXP];
    const int t = threadIdx.x;
    if (t < NEXP) cnt[t] = 0;
    __syncthreads();
    for (int q = t; q < NPAIR; q += 1024) atomicAdd(&cnt[eidx[q]], 1);
    __syncthreads();
    if (t == 0) {
        int s = 0, nt = 0;
        for (int e = 0; e < NEXP; e++) {
            cur[e] = s;
            for (int mb = 0; mb < cnt[e]; mb += 128)
                tbl[nt++] = int4{e, mb, s, cnt[e]};
            s += cnt[e];
        }
        for (; nt < MAXTILE; nt++) tbl[nt] = int4{0, 0, 0, 0};
    }
    __syncthreads();
    for (int q = t; q < NPAIR; q += 1024) {
        int e = eidx[q];
        int pos = atomicAdd(&cur[e], 1);
        slot_q[pos] = q;
    }
}

// ============================================================================
// GEMM1 + SwiGLU: 128(M) x 64(N out) tile, BK=64, depth-2 counted-vmcnt
// pipeline (T3+T4): batch t is waited with vmcnt(8) AFTER batch t+1 is
// issued -> each load batch gets a full K-step (~800cy) of cover; drain to
// 0 only on the last iteration. Two barriers/step (B1: data ready; B2:
// readers done before next overwrite). LDS 64KB -> 2 blocks/CU.
// ============================================================================
__launch_bounds__(256)
__global__ void gemm1_swiglu(const unsigned short* __restrict__ xb,
                             const unsigned short* __restrict__ w13b,
                             const int4* __restrict__ tbl,
                             const int* __restrict__ slot_q,
                             unsigned short* __restrict__ pbuf) {
    const int4 tt = tbl[blockIdx.y];
    const int e = tt.x, mbase = tt.y, off0 = tt.z, ne = tt.w;
    if (mbase >= ne) return;
    const int n0 = blockIdx.x * 64;

    __shared__ __align__(16) unsigned short As[2][128 * 64];
    __shared__ __align__(16) unsigned short Bs[2][128 * 64];

    const int t    = threadIdx.x;
    const int lane = t & 63;
    const int wid  = t >> 6;

    const int rr = t >> 3;
    const int g  = (t & 7) ^ (rr & 7);
    const unsigned short* pA[4];
    const unsigned short* pB[4];
    const unsigned short* wb1 = w13b + (size_t)e * (2 * IDIM) * DDIM;
    #pragma unroll
    for (int c = 0; c < 4; c++) {
        int row = c * 32 + rr;                      // 0..127
        int sl = mbase + row; if (sl > ne - 1) sl = ne - 1;
        pA[c] = xb + (size_t)(slot_q[off0 + sl] >> 1) * DDIM + g * 8;
        int wrow = (row < 64) ? (n0 + row) : (IDIM + n0 + (row - 64));  // w1 | w3
        pB[c] = wb1 + (size_t)wrow * DDIM + g * 8;
    }
    const int lo = wid * 512;   // + c*2048 within each buffer

    const int wm = wid >> 1, wn = wid & 1;
    const int quad = lane >> 4, l16 = lane & 15;
    const int rsw = l16 & 7;
    const int co0 = (quad ^ rsw) * 8;
    const int co1 = ((quad + 4) ^ rsw) * 8;

    floatx4 acc1[4][2], acc3[4][2];
    #pragma unroll
    for (int i = 0; i < 4; i++)
        #pragma unroll
        for (int j = 0; j < 2; j++) {
            acc1[i][j] = floatx4{0.f, 0.f, 0.f, 0.f};
            acc3[i][j] = floatx4{0.f, 0.f, 0.f, 0.f};
        }

    // prologue: stage tile 0 into buf 0 (8 loads in flight; no wait here)
    #pragma unroll
    for (int c = 0; c < 4; c++) {
        gload_lds16(pA[c], &As[0][lo + c * 2048]);
        gload_lds16(pB[c], &Bs[0][lo + c * 2048]);
    }
    __builtin_amdgcn_sched_barrier(0);

    int cur = 0;
    for (int it = 0; it < DDIM / 64; ++it) {        // 16 K-steps
        if (it + 1 < DDIM / 64) {
            // issue batch t+1 into buf^1 (its readers finished at B2 of t-1)
            const int ko = (it + 1) * 64;
            #pragma unroll
            for (int c = 0; c < 4; c++) {
                gload_lds16(pA[c] + ko, &As[cur ^ 1][lo + c * 2048]);
                gload_lds16(pB[c] + ko, &Bs[cur ^ 1][lo + c * 2048]);
            }
            __builtin_amdgcn_sched_barrier(0);
            asm volatile("s_waitcnt vmcnt(8)" ::: "memory");   // batch t landed
        } else {
            asm volatile("s_waitcnt vmcnt(0)" ::: "memory");   // final drain
        }
        __builtin_amdgcn_s_barrier();               // B1: tile t ready for all
        __builtin_amdgcn_sched_barrier(0);

        __builtin_amdgcn_s_setprio(1);
        #pragma unroll
        for (int h = 0; h < 2; ++h) {
            const int co = h ? co1 : co0;
            short8 af[4], b1f[2], b3f[2];
            #pragma unroll
            for (int mi = 0; mi < 4; mi++)
                af[mi] = *(short8*)&As[cur][(wm * 64 + mi * 16 + l16) * 64 + co];
            #pragma unroll
            for (int ni = 0; ni < 2; ni++) {
                b1f[ni] = *(short8*)&Bs[cur][(wn * 32 + ni * 16 + l16) * 64 + co];
                b3f[ni] = *(short8*)&Bs[cur][(64 + wn * 32 + ni * 16 + l16) * 64 + co];
            }
            #pragma unroll
            for (int mi = 0; mi < 4; mi++)
                #pragma unroll
                for (int ni = 0; ni < 2; ni++) {
                    acc1[mi][ni] = __builtin_amdgcn_mfma_f32_16x16x32_bf16(af[mi], b1f[ni], acc1[mi][ni], 0, 0, 0);
                    acc3[mi][ni] = __builtin_amdgcn_mfma_f32_16x16x32_bf16(af[mi], b3f[ni], acc3[mi][ni], 0, 0, 0);
                }
        }
        __builtin_amdgcn_s_setprio(0);
        __builtin_amdgcn_s_barrier();               // B2: readers done with buf[cur]
        __builtin_amdgcn_sched_barrier(0);
        cur ^= 1;
    }

    #pragma unroll
    for (int mi = 0; mi < 4; mi++) {
        #pragma unroll
        for (int ni = 0; ni < 2; ni++) {
            const int col = n0 + wn * 32 + ni * 16 + l16;
            #pragma unroll
            for (int rw = 0; rw < 4; rw++) {
                const int s2 = mbase + wm * 64 + mi * 16 + quad * 4 + rw;
                if (s2 < ne) {
                    float v1 = acc1[mi][ni][rw];
                    float v3 = acc3[mi][ni][rw];
                    float pv = v1 / (1.f + __expf(-v1)) * v3;
                    __hip_bfloat16 pb = __float2bfloat16(pv);
                    pbuf[(size_t)(off0 + s2) * IDIM + col] = *(unsigned short*)&pb;
                }
            }
        }
    }
}

// ============================================================================
// GEMM2: 128(M) x 64(N) tile, full K=2048, direct fp32 store to out.
// Same depth-2 counted-vmcnt pipeline (6 loads/batch -> vmcnt(6)).
// LDS 48KB -> 3 blocks/CU. grid (16, MAXTILE).
// ============================================================================
__launch_bounds__(256)
__global__ void gemm2_out(const unsigned short* __restrict__ pbuf,
                          const unsigned short* __restrict__ w2b,
                          const int4* __restrict__ tbl,
                          const int* __restrict__ slot_q,
                          float* __restrict__ out) {
    const int4 tt = tbl[blockIdx.y];
    const int e = tt.x, mbase = tt.y, off0 = tt.z, ne = tt.w;
    if (mbase >= ne) return;
    const int n0 = blockIdx.x * 64;

    __shared__ __align__(16) unsigned short As[2][128 * 64];
    __shared__ __align__(16) unsigned short Bs[2][64 * 64];

    const int t    = threadIdx.x;
    const int lane = t & 63;
    const int wid  = t >> 6;

    const int rr = t >> 3;
    const int g  = (t & 7) ^ (rr & 7);
    const unsigned short* pA[4];
    const unsigned short* pB[2];
    const unsigned short* wb = w2b + (size_t)e * DDIM * IDIM;
    #pragma unroll
    for (int c = 0; c < 4; c++) {
        int row = c * 32 + rr;                      // 0..127
        int sl = mbase + row; if (sl > ne - 1) sl = ne - 1;
        pA[c] = pbuf + (size_t)(off0 + sl) * IDIM + g * 8;
    }
    #pragma unroll
    for (int c = 0; c < 2; c++) {
        int row = c * 32 + rr;                      // 0..63
        pB[c] = wb + (size_t)(n0 + row) * IDIM + g * 8;
    }
    const int lo = wid * 512;

    const int wm = wid >> 1, wn = wid & 1;
    const int quad = lane >> 4, l16 = lane & 15;
    const int rsw = l16 & 7;
    const int co0 = (quad ^ rsw) * 8;
    const int co1 = ((quad + 4) ^ rsw) * 8;

    floatx4 acc[4][2];
    #pragma unroll
    for (int i = 0; i < 4; i++)
        #pragma unroll
        for (int j = 0; j < 2; j++) acc[i][j] = floatx4{0.f, 0.f, 0.f, 0.f};

    // prologue: stage tile 0 into buf 0
    #pragma unroll
    for (int c = 0; c < 4; c++)
        gload_lds16(pA[c], &As[0][lo + c * 2048]);
    #pragma unroll
    for (int c = 0; c < 2; c++)
        gload_lds16(pB[c], &Bs[0][lo + c * 2048]);
    __builtin_amdgcn_sched_barrier(0);

    int cur = 0;
    for (int it = 0; it < IDIM / 64; ++it) {        // 32 K-steps
        if (it + 1 < IDIM / 64) {
            const int ko = (it + 1) * 64;
            #pragma unroll
            for (int c = 0; c < 4; c++)
                gload_lds16(pA[c] + ko, &As[cur ^ 1][lo + c * 2048]);
            #pragma unroll
            for (int c = 0; c < 2; c++)
                gload_lds16(pB[c] + ko, &Bs[cur ^ 1][lo + c * 2048]);
            __builtin_amdgcn_sched_barrier(0);
            asm volatile("s_waitcnt vmcnt(6)" ::: "memory");   // batch t landed
        } else {
            asm volatile("s_waitcnt vmcnt(0)" ::: "memory");
        }
        __builtin_amdgcn_s_barrier();               // B1
        __builtin_amdgcn_sched_barrier(0);

        __builtin_amdgcn_s_setprio(1);
        #pragma unroll
        for (int h = 0; h < 2; ++h) {
            const int co = h ? co1 : co0;
            short8 af[4], bf[2];
            #pragma unroll
            for (int mi = 0; mi < 4; mi++)
                af[mi] = *(short8*)&As[cur][(wm * 64 + mi * 16 + l16) * 64 + co];
            #pragma unroll
            for (int ni = 0; ni < 2; ni++)
                bf[ni] = *(short8*)&Bs[cur][(wn * 32 + ni * 16 + l16) * 64 + co];
            #pragma unroll
            for (int mi = 0; mi < 4; mi++)
                #pragma unroll
                for (int ni = 0; ni < 2; ni++)
                    acc[mi][ni] = __builtin_amdgcn_mfma_f32_16x16x32_bf16(af[mi], bf[ni], acc[mi][ni], 0, 0, 0);
        }
        __builtin_amdgcn_s_setprio(0);
        __builtin_amdgcn_s_barrier();               // B2
        __builtin_amdgcn_sched_barrier(0);
        cur ^= 1;
    }

    #pragma unroll
    for (int mi = 0; mi < 4; mi++) {
        #pragma unroll
        for (int rw = 0; rw < 4; rw++) {
            const int s2 = mbase + wm * 64 + mi * 16 + quad * 4 + rw;
            if (s2 < ne) {
                const int qq = slot_q[off0 + s2];
                float* orow = out + (size_t)qq * DDIM;
                #pragma unroll
                for (int ni = 0; ni < 2; ni++)
                    orow[n0 + wn * 32 + ni * 16 + l16] = acc[mi][ni][rw];
            }
        }
    }
}

// ============================================================================
extern "C" void kernel_launch(void* const* d_in, const int* in_sizes, int n_in,
                              void* d_out, int out_size, void* d_ws, size_t ws_size,
                              hipStream_t stream) {
    const float* x    = (const float*)d_in[0];
    const float* w13  = (const float*)d_in[1];
    const float* w2   = (const float*)d_in[2];
    const int*   eidx = (const int*)d_in[3];
    float* out = (float*)d_out;

    // ws layout:
    //   [128,768) tile tbl; [1024,17408) slot_q; [OFF_XB,+4MB) xb;
    //   [OFF_W13B,+64MB) w13b; [OFF_W2B,+32MB) w2b; [OFF_PBUF,+16MB) pbuf
    const size_t OFF_XB   = 65536;
    const size_t OFF_W13B = OFF_XB + (size_t)4 * 1024 * 1024;
    const size_t OFF_W2B  = OFF_W13B + (size_t)64 * 1024 * 1024;
    const size_t OFF_PBUF = OFF_W2B + (size_t)32 * 1024 * 1024;

    int4* tbl   = (int4*)((char*)d_ws + 128);
    int* slot_q = (int*)((char*)d_ws + 1024);
    unsigned short* xb   = (unsigned short*)((char*)d_ws + OFF_XB);
    unsigned short* w13b = (unsigned short*)((char*)d_ws + OFF_W13B);
    unsigned short* w2b  = (unsigned short*)((char*)d_ws + OFF_W2B);
    unsigned short* pbuf = (unsigned short*)((char*)d_ws + OFF_PBUF);

    hipLaunchKernelGGL(route_kernel, dim3(1), dim3(1024), 0, stream, eidx, tbl, slot_q);
    hipLaunchKernelGGL(cvt_all, dim3(6400), dim3(256), 0, stream,
                       (const fvec4*)x, (const fvec4*)w13, (const fvec4*)w2,
                       (uint4*)xb, (uint4*)w13b, (uint4*)w2b);
    hipLaunchKernelGGL(gemm1_swiglu, dim3(IDIM / 64, MAXTILE), dim3(256), 0, stream,
                       xb, w13b, tbl, slot_q, pbuf);
    hipLaunchKernelGGL(gemm2_out, dim3(DDIM / 64, MAXTILE), dim3(256), 0, stream,
                       pbuf, w2b, tbl, slot_q, out);
}